// Round 1
// baseline (8725.040 us; speedup 1.0000x reference)
//
#include <hip/hip_runtime.h>
#include <math.h>

// ---------------------------------------------------------------------------
// MultiLevelGlobalContext — fp32 correctness-first baseline.
// Levels: ci={256,512,1024,2048}, hw={10000,2500,625,169}, ni={256,192,128,64}
// B=8, C=256, G=640 (=sum ni).
// ---------------------------------------------------------------------------

#define BB 8
#define CC 256
#define GG 640

// ======================= Kernel A: C[b,o,p] = act(W@X + bias) (+res) ========
// W: (O,K) row-major, optional batch stride sW (0 => shared).
// X: X + b*sX + offX + k*ldx + p
// C: C + b*sC + offC + o*ldc + p
// res: res + b*sR + offR + o*ldr + p  (nullable)
__global__ __launch_bounds__(256) void gemmA(
    const float* __restrict__ W, long sW,
    const float* __restrict__ X, long sX, int ldx, long offX,
    float* __restrict__ Cd, long sC, int ldc, long offC,
    const float* __restrict__ bias,
    const float* __restrict__ res, long sR, int ldr, long offR,
    int O, int K, int P, int relu, int accum)
{
    __shared__ float Ws[16][64];
    __shared__ float Xs[16][64];
    const int tid = threadIdx.x;
    const int tx = tid & 15;          // -> p
    const int ty = tid >> 4;          // -> o
    const int b  = blockIdx.z;
    const int o0 = blockIdx.y * 64;
    const int p0 = blockIdx.x * 64;

    const float* Wb = W + (long)b * sW;
    const float* Xb = X + (long)b * sX + offX;

    float acc[4][4] = {};

    const int wo = tid >> 2;           // 0..63 (row of W tile)
    const int wk = (tid & 3) * 4;      // 0,4,8,12
    const int xp = tid & 63;           // 0..63 (col of X tile)
    const int xq = tid >> 6;           // 0..3

    for (int k0 = 0; k0 < K; k0 += 16) {
        #pragma unroll
        for (int u = 0; u < 4; ++u) {
            int kk = wk + u;
            float v = 0.f;
            if (o0 + wo < O && k0 + kk < K) v = Wb[(long)(o0 + wo) * K + k0 + kk];
            Ws[kk][wo] = v;
        }
        #pragma unroll
        for (int u = 0; u < 4; ++u) {
            int kk = xq * 4 + u;
            float v = 0.f;
            if (p0 + xp < P && k0 + kk < K) v = Xb[(long)(k0 + kk) * ldx + (p0 + xp)];
            Xs[kk][xp] = v;
        }
        __syncthreads();
        #pragma unroll
        for (int kk = 0; kk < 16; ++kk) {
            float4 wv = *(const float4*)&Ws[kk][ty * 4];
            float4 xv = *(const float4*)&Xs[kk][tx * 4];
            float wa[4] = {wv.x, wv.y, wv.z, wv.w};
            float xa[4] = {xv.x, xv.y, xv.z, xv.w};
            #pragma unroll
            for (int i = 0; i < 4; ++i)
                #pragma unroll
                for (int j = 0; j < 4; ++j)
                    acc[i][j] += wa[i] * xa[j];
        }
        __syncthreads();
    }

    #pragma unroll
    for (int i = 0; i < 4; ++i) {
        int o = o0 + ty * 4 + i;
        if (o >= O) continue;
        #pragma unroll
        for (int j = 0; j < 4; ++j) {
            int p = p0 + tx * 4 + j;
            if (p >= P) continue;
            float v = acc[i][j];
            if (bias) v += bias[o];
            if (relu) v = fmaxf(v, 0.f);
            if (res)  v += res[(long)b * sR + offR + (long)o * ldr + p];
            long ci_ = (long)b * sC + offC + (long)o * ldc + p;
            if (accum) Cd[ci_] += v; else Cd[ci_] = v;
        }
    }
}

// ============ Kernel B: C[b,i,j] = sum_k A[b,i,k] * Bt[b,j,k] ==============
// Contraction axis k contiguous on both sides.
__global__ __launch_bounds__(256) void gemmABT(
    const float* __restrict__ A, long sA, int lda, long offA,
    const float* __restrict__ Bm, long sB, int ldb, long offB,
    float* __restrict__ Cd, long sC, int ldc, long offC,
    int I, int J, int K)
{
    __shared__ float As[16][64];
    __shared__ float Bs[16][64];
    const int tid = threadIdx.x;
    const int tx = tid & 15;          // -> j
    const int ty = tid >> 4;          // -> i
    const int b  = blockIdx.z;
    const int i0 = blockIdx.y * 64;
    const int j0 = blockIdx.x * 64;

    const float* Ab = A  + (long)b * sA + offA;
    const float* Bb = Bm + (long)b * sB + offB;

    float acc[4][4] = {};

    const int rr = tid >> 2;          // 0..63
    const int rk = (tid & 3) * 4;     // 0,4,8,12

    for (int k0 = 0; k0 < K; k0 += 16) {
        #pragma unroll
        for (int u = 0; u < 4; ++u) {
            int kk = rk + u;
            float va = 0.f, vb = 0.f;
            if (k0 + kk < K) {
                if (i0 + rr < I) va = Ab[(long)(i0 + rr) * lda + k0 + kk];
                if (j0 + rr < J) vb = Bb[(long)(j0 + rr) * ldb + k0 + kk];
            }
            As[kk][rr] = va;
            Bs[kk][rr] = vb;
        }
        __syncthreads();
        #pragma unroll
        for (int kk = 0; kk < 16; ++kk) {
            float4 av = *(const float4*)&As[kk][ty * 4];
            float4 bv = *(const float4*)&Bs[kk][tx * 4];
            float aa[4] = {av.x, av.y, av.z, av.w};
            float ba[4] = {bv.x, bv.y, bv.z, bv.w};
            #pragma unroll
            for (int i = 0; i < 4; ++i)
                #pragma unroll
                for (int j = 0; j < 4; ++j)
                    acc[i][j] += aa[i] * ba[j];
        }
        __syncthreads();
    }

    #pragma unroll
    for (int i = 0; i < 4; ++i) {
        int r = i0 + ty * 4 + i;
        if (r >= I) continue;
        #pragma unroll
        for (int j = 0; j < 4; ++j) {
            int c = j0 + tx * 4 + j;
            if (c >= J) continue;
            Cd[(long)b * sC + offC + (long)r * ldc + c] = acc[i][j];
        }
    }
}

// ===== scores[b,p,n] = sum_o qn[b,o,p] * lcnT[b,n,o]  (K=256 fixed) ========
__global__ __launch_bounds__(256) void scoresKer(
    const float* __restrict__ q, const float* __restrict__ lcnT,
    float* __restrict__ S, int hw, int ni)
{
    __shared__ float Qs[16][64];
    __shared__ float Ls[16][64];
    const int tid = threadIdx.x;
    const int tx = tid & 15;          // -> n
    const int ty = tid >> 4;          // -> p
    const int b  = blockIdx.z;
    const int n0 = blockIdx.x * 64;
    const int p0 = blockIdx.y * 64;

    const float* qb = q    + (long)b * CC * hw;
    const float* lb = lcnT + (long)b * ni * CC;

    float acc[4][4] = {};

    const int pp = tid & 63;
    const int pq = tid >> 6;
    const int nr = tid >> 2;
    const int nk = (tid & 3) * 4;

    for (int k0 = 0; k0 < CC; k0 += 16) {
        #pragma unroll
        for (int u = 0; u < 4; ++u) {
            int kk = pq * 4 + u;
            Qs[kk][pp] = (p0 + pp < hw) ? qb[(long)(k0 + kk) * hw + p0 + pp] : 0.f;
        }
        #pragma unroll
        for (int u = 0; u < 4; ++u) {
            int kk = nk + u;
            Ls[kk][nr] = (n0 + nr < ni) ? lb[(long)(n0 + nr) * CC + k0 + kk] : 0.f;
        }
        __syncthreads();
        #pragma unroll
        for (int kk = 0; kk < 16; ++kk) {
            float4 qv = *(const float4*)&Qs[kk][ty * 4];
            float4 lv = *(const float4*)&Ls[kk][tx * 4];
            float qa[4] = {qv.x, qv.y, qv.z, qv.w};
            float la[4] = {lv.x, lv.y, lv.z, lv.w};
            #pragma unroll
            for (int i = 0; i < 4; ++i)
                #pragma unroll
                for (int j = 0; j < 4; ++j)
                    acc[i][j] += qa[i] * la[j];
        }
        __syncthreads();
    }

    #pragma unroll
    for (int i = 0; i < 4; ++i) {
        int p = p0 + ty * 4 + i;
        if (p >= hw) continue;
        #pragma unroll
        for (int j = 0; j < 4; ++j) {
            int n = n0 + tx * 4 + j;
            if (n >= ni) continue;
            S[((long)b * hw + p) * ni + n] = acc[i][j];
        }
    }
}

// ======== fscale[b,p] = (sum_c f) / max(||f||,eps) * sqrt(ci) ==============
__global__ void posStats(const float* __restrict__ f, float* __restrict__ fscale,
                         int ci, int hw, float sq)
{
    int b = blockIdx.y;
    int p = blockIdx.x * 256 + threadIdx.x;
    if (p >= hw) return;
    const float* fb = f + (long)b * ci * hw + p;
    float s = 0.f, ss = 0.f;
    for (int c = 0; c < ci; ++c) { float v = fb[(long)c * hw]; s += v; ss += v * v; }
    fscale[(long)b * hw + p] = s / fmaxf(sqrtf(ss), 1e-12f) * sq;
}

// ==== scale[b,p] = fscale[b,p] / max(||sem[b,:,p]||,eps) ===================
__global__ void enScale(const float* __restrict__ sem, float* __restrict__ fscale,
                        int ni, int hw)
{
    int b = blockIdx.y;
    int p = blockIdx.x * 256 + threadIdx.x;
    if (p >= hw) return;
    const float* sb = sem + (long)b * ni * hw + p;
    float ss = 0.f;
    for (int n = 0; n < ni; ++n) { float v = sb[(long)n * hw]; ss += v * v; }
    fscale[(long)b * hw + p] = fscale[(long)b * hw + p] / fmaxf(sqrtf(ss), 1e-12f);
}

// ==== softmax over p of sem[b,n,p]*scale[b,p], in place ====================
__global__ __launch_bounds__(256) void softmaxHW(float* __restrict__ sem,
                                                 const float* __restrict__ scale,
                                                 int ni, int hw)
{
    int b = blockIdx.y, n = blockIdx.x;
    float* row = sem + ((long)b * ni + n) * hw;
    const float* sc = scale + (long)b * hw;
    __shared__ float red[256];
    int tid = threadIdx.x;

    float m = -1e30f;
    for (int p = tid; p < hw; p += 256) m = fmaxf(m, row[p] * sc[p]);
    red[tid] = m; __syncthreads();
    for (int s = 128; s > 0; s >>= 1) {
        if (tid < s) red[tid] = fmaxf(red[tid], red[tid + s]);
        __syncthreads();
    }
    m = red[0]; __syncthreads();

    float sum = 0.f;
    for (int p = tid; p < hw; p += 256) sum += __expf(row[p] * sc[p] - m);
    red[tid] = sum; __syncthreads();
    for (int s = 128; s > 0; s >>= 1) {
        if (tid < s) red[tid] += red[tid + s];
        __syncthreads();
    }
    float inv = 1.0f / red[0];

    for (int p = tid; p < hw; p += 256) row[p] = __expf(row[p] * sc[p] - m) * inv;
}

// ==== softmax over n (contiguous), one wave per position ===================
__global__ void softmaxN(float* __restrict__ S, int hw, int ni)
{
    int b = blockIdx.y;
    int wav = threadIdx.x >> 6, lane = threadIdx.x & 63;
    int p = blockIdx.x * 4 + wav;
    if (p >= hw) return;
    float* row = S + ((long)b * hw + p) * ni;
    float m = -1e30f;
    for (int n = lane; n < ni; n += 64) m = fmaxf(m, row[n]);
    for (int off = 32; off > 0; off >>= 1) m = fmaxf(m, __shfl_xor(m, off));
    float s = 0.f;
    for (int n = lane; n < ni; n += 64) s += __expf(row[n] - m);
    for (int off = 32; off > 0; off >>= 1) s += __shfl_xor(s, off);
    float inv = 1.f / s;
    for (int n = lane; n < ni; n += 64) row[n] = __expf(row[n] - m) * inv;
}

// ==== lcr[b,col] = 1/max(||g2[b,:,col]||,eps), col in [0,640) ==============
__global__ void lcRnorm(const float* __restrict__ g2, float* __restrict__ lcr)
{
    int b = blockIdx.y;
    int col = blockIdx.x * 256 + threadIdx.x;
    if (col >= GG) return;
    const float* gb = g2 + (long)b * CC * GG + col;
    float ss = 0.f;
    for (int o = 0; o < CC; ++o) { float v = gb[o * GG]; ss += v * v; }
    lcr[b * GG + col] = 1.f / fmaxf(sqrtf(ss), 1e-12f);
}

// ==== lcnT[b,n,o] = g2[b,o,ptr+n] * lcr[b,ptr+n] ===========================
__global__ void buildLcnT(const float* __restrict__ g2, const float* __restrict__ lcr,
                          float* __restrict__ lcnT, int ni, int ptr)
{
    long t = (long)blockIdx.x * 256 + threadIdx.x;
    if (t >= (long)BB * ni * CC) return;
    int o = (int)(t & (CC - 1));
    long r = t >> 8;
    int n = (int)(r % ni);
    int b = (int)(r / ni);
    lcnT[t] = g2[(long)b * CC * GG + (long)o * GG + ptr + n] * lcr[b * GG + ptr + n];
}

// ==== normalize q columns over o, in place =================================
__global__ void qNorm(float* __restrict__ q, int hw)
{
    int b = blockIdx.y;
    int p = blockIdx.x * 256 + threadIdx.x;
    if (p >= hw) return;
    float* qb = q + (long)b * CC * hw + p;
    float ss = 0.f;
    for (int o = 0; o < CC; ++o) { float v = qb[(long)o * hw]; ss += v * v; }
    float r = 1.f / fmaxf(sqrtf(ss), 1e-12f);
    for (int o = 0; o < CC; ++o) qb[(long)o * hw] *= r;
}

// ===========================================================================
extern "C" void kernel_launch(void* const* d_in, const int* in_sizes, int n_in,
                              void* d_out, int out_size, void* d_ws, size_t ws_size,
                              hipStream_t stream)
{
    (void)n_in; (void)out_size; (void)ws_size;
    static const int  CI[4]  = {256, 512, 1024, 2048};
    static const int  NI[4]  = {256, 192, 128, 64};
    static const int  HWs[4] = {10000, 2500, 625, 169};
    static const int  PTR[4] = {0, 256, 448, 576};
    static const long OUTOFF[4] = {0, 20480000L, 25600000L, 26880000L};

    const float* feat[4];
    for (int i = 0; i < 4; ++i) feat[i] = (const float*)d_in[i];

    const float *w_sem[4], *w_emb[4], *w_q[4], *w_out[4], *w_res[4];
    // Dict order: (w_sem_i, w_emb_i, w_q_i, w_out_i, w_res_i) per level.
    // Defensive: detect grouped (signature) order via in_sizes[5].
    bool grouped = (in_sizes[5] == 192 * 512);
    for (int i = 0; i < 4; ++i) {
        if (grouped) {
            w_sem[i] = (const float*)d_in[4 + i];
            w_emb[i] = (const float*)d_in[8 + i];
            w_q[i]   = (const float*)d_in[12 + i];
            w_out[i] = (const float*)d_in[16 + i];
            w_res[i] = (const float*)d_in[20 + i];
        } else {
            int base = 4 + 5 * i;
            w_sem[i] = (const float*)d_in[base + 0];
            w_emb[i] = (const float*)d_in[base + 1];
            w_q[i]   = (const float*)d_in[base + 2];
            w_out[i] = (const float*)d_in[base + 3];
            w_res[i] = (const float*)d_in[base + 4];
        }
    }
    const float* gw1 = (const float*)d_in[24];
    const float* gb1 = (const float*)d_in[25];
    const float* gw2 = (const float*)d_in[26];
    const float* gb2 = (const float*)d_in[27];
    const float* gw3 = (const float*)d_in[28];
    const float* gb3 = (const float*)d_in[29];
    const float* mw1 = (const float*)d_in[30];
    const float* mb1 = (const float*)d_in[31];
    const float* mw2 = (const float*)d_in[32];
    const float* mb2 = (const float*)d_in[33];
    const float* mw3 = (const float*)d_in[34];
    const float* mb3 = (const float*)d_in[35];

    float* ws   = (float*)d_ws;
    float* Abuf = ws;  ws += 20480000;   // sem/attn (ph1), q/wc (ph2)
    float* Bbuf = ws;  ws += 20480000;   // emb (ph1), scores (ph2)
    float* scl  = ws;  ws += 80000;      // per-position scale
    float* ctxg = ws;  ws += 1310720;    // contexts packed (B,256,640)
    float* gbuf = ws;  ws += 1310720;    // refined g
    float* g2   = ws;  ws += 1310720;    // after master gcn
    float* h1   = ws;  ws += 327680;     // (B,64,640)
    float* h2   = ws;  ws += 327680;
    float* lcr  = ws;  ws += 5120;       // (B,640)
    float* lcnT = ws;  ws += 524288;     // (B,ni,256) max

    float* outp = (float*)d_out;

    auto launchA = [&](const float* W, long sW,
                       const float* X, long sX, int ldx, long offX,
                       float* Cd, long sC, int ldc, long offC,
                       const float* bias,
                       const float* res, long sR, int ldr, long offR,
                       int O, int K, int P, int relu, int accum) {
        dim3 g((P + 63) / 64, (O + 63) / 64, BB);
        gemmA<<<g, 256, 0, stream>>>(W, sW, X, sX, ldx, offX, Cd, sC, ldc, offC,
                                     bias, res, sR, ldr, offR, O, K, P, relu, accum);
    };

    // ---------------- Phase 1: per-level attention -> contexts -------------
    for (int i = 0; i < 4; ++i) {
        int ci = CI[i], ni = NI[i], hw = HWs[i];
        dim3 bpg((hw + 255) / 256, BB);
        posStats<<<bpg, 256, 0, stream>>>(feat[i], scl, ci, hw, sqrtf((float)ci));
        // sem = w_sem @ f  -> Abuf
        launchA(w_sem[i], 0, feat[i], (long)ci * hw, hw, 0,
                Abuf, (long)ni * hw, hw, 0, nullptr, nullptr, 0, 0, 0,
                ni, ci, hw, 0, 0);
        enScale<<<bpg, 256, 0, stream>>>(Abuf, scl, ni, hw);
        // emb = w_emb @ f -> Bbuf
        launchA(w_emb[i], 0, feat[i], (long)ci * hw, hw, 0,
                Bbuf, (long)CC * hw, hw, 0, nullptr, nullptr, 0, 0, 0,
                CC, ci, hw, 0, 0);
        // attn = softmax_p(sem * scale)  (in place over Abuf)
        softmaxHW<<<dim3(ni, BB), 256, 0, stream>>>(Abuf, scl, ni, hw);
        // ctx[b,o,n] = sum_p emb * attn -> ctxg slice
        gemmABT<<<dim3(ni / 64, CC / 64, BB), 256, 0, stream>>>(
            Bbuf, (long)CC * hw, hw, 0,
            Abuf, (long)ni * hw, hw, 0,
            ctxg, (long)CC * GG, GG, PTR[i],
            CC, ni, hw);
    }

    // ---------------- GCN per level + residual -> gbuf ---------------------
    for (int i = 0; i < 4; ++i) {
        int ni = NI[i];
        launchA(gw1 + (long)i * 64 * CC, 0, ctxg, (long)CC * GG, GG, PTR[i],
                h1, (long)64 * GG, GG, PTR[i], gb1 + i * 64, nullptr, 0, 0, 0,
                64, CC, ni, 1, 0);
        launchA(gw2 + (long)i * 64 * 64, 0, h1, (long)64 * GG, GG, PTR[i],
                h2, (long)64 * GG, GG, PTR[i], gb2 + i * 64, nullptr, 0, 0, 0,
                64, 64, ni, 1, 0);
        launchA(gw3 + (long)i * CC * 64, 0, h2, (long)64 * GG, GG, PTR[i],
                gbuf, (long)CC * GG, GG, PTR[i], gb3 + i * CC,
                ctxg, (long)CC * GG, GG, PTR[i],
                CC, 64, ni, 0, 0);
    }
    // ---------------- Master GCN + residual -> g2 --------------------------
    launchA(mw1, 0, gbuf, (long)CC * GG, GG, 0, h1, (long)64 * GG, GG, 0,
            mb1, nullptr, 0, 0, 0, 64, CC, GG, 1, 0);
    launchA(mw2, 0, h1, (long)64 * GG, GG, 0, h2, (long)64 * GG, GG, 0,
            mb2, nullptr, 0, 0, 0, 64, 64, GG, 1, 0);
    launchA(mw3, 0, h2, (long)64 * GG, GG, 0, g2, (long)CC * GG, GG, 0,
            mb3, gbuf, (long)CC * GG, GG, 0, CC, 64, GG, 0, 0);

    lcRnorm<<<dim3(3, BB), 256, 0, stream>>>(g2, lcr);

    // ---------------- Phase 2: per-level read-out attention ----------------
    for (int i = 0; i < 4; ++i) {
        int ci = CI[i], ni = NI[i], hw = HWs[i];
        long tot = (long)BB * ni * CC;
        buildLcnT<<<dim3((unsigned)((tot + 255) / 256)), 256, 0, stream>>>(g2, lcr, lcnT, ni, PTR[i]);
        // q = w_q @ f -> Abuf
        launchA(w_q[i], 0, feat[i], (long)ci * hw, hw, 0,
                Abuf, (long)CC * hw, hw, 0, nullptr, nullptr, 0, 0, 0,
                CC, ci, hw, 0, 0);
        qNorm<<<dim3((hw + 255) / 256, BB), 256, 0, stream>>>(Abuf, hw);
        // scores[b,p,n] -> Bbuf
        scoresKer<<<dim3(ni / 64, (hw + 63) / 64, BB), 256, 0, stream>>>(
            Abuf, lcnT, Bbuf, hw, ni);
        softmaxN<<<dim3((hw + 3) / 4, BB), 256, 0, stream>>>(Bbuf, hw, ni);
        // wc[b,o,p] = sum_n lc[b,o,n]*aw[b,p,n] -> Abuf (q dead)
        gemmABT<<<dim3((hw + 63) / 64, CC / 64, BB), 256, 0, stream>>>(
            g2, (long)CC * GG, GG, PTR[i],
            Bbuf, (long)hw * ni, ni, 0,
            Abuf, (long)CC * hw, hw, 0,
            CC, hw, ni);
        // out = w_res @ f ; += w_out @ wc
        launchA(w_res[i], 0, feat[i], (long)ci * hw, hw, 0,
                outp, (long)CC * hw, hw, OUTOFF[i], nullptr, nullptr, 0, 0, 0,
                CC, ci, hw, 0, 0);
        launchA(w_out[i], 0, Abuf, (long)CC * hw, hw, 0,
                outp, (long)CC * hw, hw, OUTOFF[i], nullptr, nullptr, 0, 0, 0,
                CC, CC, hw, 0, 1);
    }
}

// Round 2
// 2741.621 us; speedup vs baseline: 3.1824x; 3.1824x over previous
//
#include <hip/hip_runtime.h>
#include <math.h>

// ---------------------------------------------------------------------------
// MultiLevelGlobalContext — bf16 MFMA rewrite.
// Levels: ci={256,512,1024,2048}, hw={10000,2500,625,169}, ni={256,192,128,64}
// B=8, C=256, G=640.
// ---------------------------------------------------------------------------

#define BB 8
#define CC 256
#define GG 640

typedef __attribute__((ext_vector_type(8))) short short8;
typedef __attribute__((ext_vector_type(4))) float f32x4;

__device__ __forceinline__ unsigned short f2bf(float f) {
    unsigned int u = __float_as_uint(f);
    u += 0x7fffu + ((u >> 16) & 1u);
    return (unsigned short)(u >> 16);
}
__device__ __forceinline__ float bf2f(unsigned short h) {
    return __uint_as_float(((unsigned int)h) << 16);
}

// ===================== bf16 MFMA GEMM: C[b] = A(M,K) @ B(N,K)^T =============
// A, B bf16 (ushort), K contiguous (lda/ldb = row stride in elements).
// modes: 0 store f32, 1 accum f32, 2 atomicAdd f32, 3 store f16, 4 store bf16
__global__ __launch_bounds__(256) void mfmaGemm(
    const unsigned short* __restrict__ A, long sA, int lda,
    const unsigned short* __restrict__ B, long sB, int ldb,
    void* __restrict__ C, long sC, int ldc, long offC,
    int M, int N, int K, int kChunks, int kChunkLen, int mode)
{
    __shared__ __align__(16) unsigned short As[128 * 40];
    __shared__ __align__(16) unsigned short Bs[128 * 40];

    const int z = blockIdx.z;
    const int b = z / kChunks, chunk = z - b * kChunks;
    const int kbeg = chunk * kChunkLen;
    if (kbeg >= K) return;
    const int kend = min(K, kbeg + kChunkLen);

    const unsigned short* Ab = A + (long)b * sA;
    const unsigned short* Bb = B + (long)b * sB;
    const int m0 = blockIdx.y * 128, n0 = blockIdx.x * 128;

    const int tid = threadIdx.x;
    const int wave = tid >> 6, lane = tid & 63;
    const int wm = (wave & 1) * 64, wn = (wave >> 1) * 64;
    const int lm = lane & 15, kq = lane >> 4;

    const bool alignedA = ((lda & 7) == 0) && ((((size_t)Ab) & 15) == 0);
    const bool alignedB = ((ldb & 7) == 0) && ((((size_t)Bb) & 15) == 0);

    f32x4 acc[4][4];
    #pragma unroll
    for (int i = 0; i < 4; ++i)
        #pragma unroll
        for (int j = 0; j < 4; ++j) acc[i][j] = (f32x4){0.f, 0.f, 0.f, 0.f};

    for (int k0 = kbeg; k0 < kend; k0 += 32) {
        // ---- stage A tile (128 rows x 32 k) ----
        #pragma unroll
        for (int l = 0; l < 2; ++l) {
            int idx = l * 256 + tid;
            int row = idx >> 2, q4 = idx & 3;
            int kg = k0 + q4 * 8;
            uint4 val = make_uint4(0u, 0u, 0u, 0u);
            int gm = m0 + row;
            if (gm < M) {
                const unsigned short* src = Ab + (long)gm * lda + kg;
                int krem = kend - kg;
                if (krem >= 8 && alignedA) {
                    val = *(const uint4*)src;
                } else if (krem > 0) {
                    __align__(16) unsigned short tmp[8] = {0,0,0,0,0,0,0,0};
                    int c = krem < 8 ? krem : 8;
                    for (int j = 0; j < c; ++j) tmp[j] = src[j];
                    val = *(const uint4*)tmp;
                }
            }
            *(uint4*)&As[row * 40 + q4 * 8] = val;
        }
        // ---- stage B tile ----
        #pragma unroll
        for (int l = 0; l < 2; ++l) {
            int idx = l * 256 + tid;
            int row = idx >> 2, q4 = idx & 3;
            int kg = k0 + q4 * 8;
            uint4 val = make_uint4(0u, 0u, 0u, 0u);
            int gn = n0 + row;
            if (gn < N) {
                const unsigned short* src = Bb + (long)gn * ldb + kg;
                int krem = kend - kg;
                if (krem >= 8 && alignedB) {
                    val = *(const uint4*)src;
                } else if (krem > 0) {
                    __align__(16) unsigned short tmp[8] = {0,0,0,0,0,0,0,0};
                    int c = krem < 8 ? krem : 8;
                    for (int j = 0; j < c; ++j) tmp[j] = src[j];
                    val = *(const uint4*)tmp;
                }
            }
            *(uint4*)&Bs[row * 40 + q4 * 8] = val;
        }
        __syncthreads();

        short8 af[4], bfr[4];
        #pragma unroll
        for (int mt = 0; mt < 4; ++mt)
            af[mt] = *(const short8*)&As[(wm + mt * 16 + lm) * 40 + kq * 8];
        #pragma unroll
        for (int nt = 0; nt < 4; ++nt)
            bfr[nt] = *(const short8*)&Bs[(wn + nt * 16 + lm) * 40 + kq * 8];
        #pragma unroll
        for (int mt = 0; mt < 4; ++mt)
            #pragma unroll
            for (int nt = 0; nt < 4; ++nt)
                acc[mt][nt] = __builtin_amdgcn_mfma_f32_16x16x32_bf16(
                    af[mt], bfr[nt], acc[mt][nt], 0, 0, 0);
        __syncthreads();
    }

    const long cbase = (long)b * sC + offC;
    #pragma unroll
    for (int mt = 0; mt < 4; ++mt) {
        #pragma unroll
        for (int nt = 0; nt < 4; ++nt) {
            int n_g = n0 + wn + nt * 16 + lm;
            if (n_g >= N) continue;
            #pragma unroll
            for (int r = 0; r < 4; ++r) {
                int m_g = m0 + wm + mt * 16 + kq * 4 + r;
                if (m_g >= M) continue;
                float v = acc[mt][nt][r];
                long ci_ = cbase + (long)m_g * ldc + n_g;
                if (mode == 0)      ((float*)C)[ci_] = v;
                else if (mode == 1) ((float*)C)[ci_] += v;
                else if (mode == 2) atomicAdd(&((float*)C)[ci_], v);
                else if (mode == 3) ((_Float16*)C)[ci_] = (_Float16)v;
                else                ((unsigned short*)C)[ci_] = f2bf(v);
            }
        }
    }
}

// ================= fp32 GEMM (small GCN layers only, round-0 code) =========
__global__ __launch_bounds__(256) void gemmA(
    const float* __restrict__ W, long sW,
    const float* __restrict__ X, long sX, int ldx, long offX,
    float* __restrict__ Cd, long sC, int ldc, long offC,
    const float* __restrict__ bias,
    const float* __restrict__ res, long sR, int ldr, long offR,
    int O, int K, int P, int relu, int accum)
{
    __shared__ float Ws[16][64];
    __shared__ float Xs[16][64];
    const int tid = threadIdx.x;
    const int tx = tid & 15;
    const int ty = tid >> 4;
    const int b  = blockIdx.z;
    const int o0 = blockIdx.y * 64;
    const int p0 = blockIdx.x * 64;

    const float* Wb = W + (long)b * sW;
    const float* Xb = X + (long)b * sX + offX;

    float acc[4][4] = {};

    const int wo = tid >> 2;
    const int wk = (tid & 3) * 4;
    const int xp = tid & 63;
    const int xq = tid >> 6;

    for (int k0 = 0; k0 < K; k0 += 16) {
        #pragma unroll
        for (int u = 0; u < 4; ++u) {
            int kk = wk + u;
            float v = 0.f;
            if (o0 + wo < O && k0 + kk < K) v = Wb[(long)(o0 + wo) * K + k0 + kk];
            Ws[kk][wo] = v;
        }
        #pragma unroll
        for (int u = 0; u < 4; ++u) {
            int kk = xq * 4 + u;
            float v = 0.f;
            if (p0 + xp < P && k0 + kk < K) v = Xb[(long)(k0 + kk) * ldx + (p0 + xp)];
            Xs[kk][xp] = v;
        }
        __syncthreads();
        #pragma unroll
        for (int kk = 0; kk < 16; ++kk) {
            float4 wv = *(const float4*)&Ws[kk][ty * 4];
            float4 xv = *(const float4*)&Xs[kk][tx * 4];
            float wa[4] = {wv.x, wv.y, wv.z, wv.w};
            float xa[4] = {xv.x, xv.y, xv.z, xv.w};
            #pragma unroll
            for (int i = 0; i < 4; ++i)
                #pragma unroll
                for (int j = 0; j < 4; ++j)
                    acc[i][j] += wa[i] * xa[j];
        }
        __syncthreads();
    }

    #pragma unroll
    for (int i = 0; i < 4; ++i) {
        int o = o0 + ty * 4 + i;
        if (o >= O) continue;
        #pragma unroll
        for (int j = 0; j < 4; ++j) {
            int p = p0 + tx * 4 + j;
            if (p >= P) continue;
            float v = acc[i][j];
            if (bias) v += bias[o];
            if (relu) v = fmaxf(v, 0.f);
            if (res)  v += res[(long)b * sR + offR + (long)o * ldr + p];
            long ci_ = (long)b * sC + offC + (long)o * ldc + p;
            if (accum) Cd[ci_] += v; else Cd[ci_] = v;
        }
    }
}

// =================== transpose+convert: dst[c][r] = src[r][c]*scale[c] =====
__global__ __launch_bounds__(256) void transCvtF(
    const float* __restrict__ src, long sS, int R, int Cc,
    unsigned short* __restrict__ dst, long sD,
    const float* __restrict__ scale, long sScale)
{
    __shared__ float tile[32][33];
    int b = blockIdx.z;
    int r0 = blockIdx.y * 32, c0 = blockIdx.x * 32;
    const float* sb = src + (long)b * sS;
    unsigned short* db = dst + (long)b * sD;
    int tr = threadIdx.x >> 5, tc = threadIdx.x & 31;
    #pragma unroll
    for (int it = 0; it < 4; ++it) {
        int r = r0 + tr + it * 8, c = c0 + tc;
        tile[tr + it * 8][tc] = (r < R && c < Cc) ? sb[(long)r * Cc + c] : 0.f;
    }
    __syncthreads();
    #pragma unroll
    for (int it = 0; it < 4; ++it) {
        int c = c0 + tr + it * 8;
        int r = r0 + tc;
        if (c < Cc && r < R) {
            float v = tile[tc][tr + it * 8];
            if (scale) v *= scale[(long)b * sScale + c];
            db[(long)c * R + r] = f2bf(v);
        }
    }
}

__global__ __launch_bounds__(256) void transCvtH(
    const _Float16* __restrict__ src, long sS, int R, int Cc,
    unsigned short* __restrict__ dst, long sD,
    const float* __restrict__ scale, long sScale)
{
    __shared__ float tile[32][33];
    int b = blockIdx.z;
    int r0 = blockIdx.y * 32, c0 = blockIdx.x * 32;
    const _Float16* sb = src + (long)b * sS;
    unsigned short* db = dst + (long)b * sD;
    int tr = threadIdx.x >> 5, tc = threadIdx.x & 31;
    #pragma unroll
    for (int it = 0; it < 4; ++it) {
        int r = r0 + tr + it * 8, c = c0 + tc;
        tile[tr + it * 8][tc] = (r < R && c < Cc) ? (float)sb[(long)r * Cc + c] : 0.f;
    }
    __syncthreads();
    #pragma unroll
    for (int it = 0; it < 4; ++it) {
        int c = c0 + tr + it * 8;
        int r = r0 + tc;
        if (c < Cc && r < R) {
            float v = tile[tc][tr + it * 8];
            if (scale) v *= scale[(long)b * sScale + c];
            db[(long)c * R + r] = f2bf(v);
        }
    }
}

// ====== per-position stats from featT rows: fscale = sum/max(norm)·sqrt ====
__global__ __launch_bounds__(256) void posStatsT(
    const unsigned short* __restrict__ featT, float* __restrict__ fscale,
    int ci, int hw, float sq)
{
    int b = blockIdx.y, p = blockIdx.x;
    const unsigned short* row = featT + ((long)b * hw + p) * ci;
    float s = 0.f, ss = 0.f;
    for (int c = threadIdx.x; c < ci; c += 256) {
        float v = bf2f(row[c]); s += v; ss += v * v;
    }
    __shared__ float rs[256], rss[256];
    int tid = threadIdx.x;
    rs[tid] = s; rss[tid] = ss; __syncthreads();
    for (int st = 128; st > 0; st >>= 1) {
        if (tid < st) { rs[tid] += rs[tid + st]; rss[tid] += rss[tid + st]; }
        __syncthreads();
    }
    if (tid == 0)
        fscale[(long)b * hw + p] = rs[0] / fmaxf(sqrtf(rss[0]), 1e-12f) * sq;
}

// ==== scale[b,p] = fscale[b,p] / max(||sem[b,:,p]||,eps)  (sem f16) ========
__global__ void enScale(const _Float16* __restrict__ sem, float* __restrict__ fscale,
                        int ni, int hw)
{
    int b = blockIdx.y;
    int p = blockIdx.x * 256 + threadIdx.x;
    if (p >= hw) return;
    const _Float16* sb = sem + (long)b * ni * hw + p;
    float ss = 0.f;
    for (int n = 0; n < ni; ++n) { float v = (float)sb[(long)n * hw]; ss += v * v; }
    fscale[(long)b * hw + p] = fscale[(long)b * hw + p] / fmaxf(sqrtf(ss), 1e-12f);
}

// ==== softmax over p of sem[b,n,p]*scale[b,p]  (f16 in, bf16 out) ==========
__global__ __launch_bounds__(256) void softmaxHW(
    const _Float16* __restrict__ sem, const float* __restrict__ scale,
    unsigned short* __restrict__ attn, int ni, int hw)
{
    int b = blockIdx.y, n = blockIdx.x;
    const _Float16* row = sem + ((long)b * ni + n) * hw;
    unsigned short* out = attn + ((long)b * ni + n) * hw;
    const float* sc = scale + (long)b * hw;
    __shared__ float red[256];
    int tid = threadIdx.x;

    float m = -1e30f;
    for (int p = tid; p < hw; p += 256) m = fmaxf(m, (float)row[p] * sc[p]);
    red[tid] = m; __syncthreads();
    for (int s = 128; s > 0; s >>= 1) {
        if (tid < s) red[tid] = fmaxf(red[tid], red[tid + s]);
        __syncthreads();
    }
    m = red[0]; __syncthreads();

    float sum = 0.f;
    for (int p = tid; p < hw; p += 256) sum += __expf((float)row[p] * sc[p] - m);
    red[tid] = sum; __syncthreads();
    for (int s = 128; s > 0; s >>= 1) {
        if (tid < s) red[tid] += red[tid + s];
        __syncthreads();
    }
    float inv = 1.0f / red[0];

    for (int p = tid; p < hw; p += 256)
        out[p] = f2bf(__expf((float)row[p] * sc[p] - m) * inv);
}

// ==== softmax over n (contiguous) of S[b,p,n] f16 -> aw bf16 ===============
__global__ void softmaxN(const _Float16* __restrict__ S, unsigned short* __restrict__ aw,
                         int hw, int ni)
{
    int b = blockIdx.y;
    int wav = threadIdx.x >> 6, lane = threadIdx.x & 63;
    int p = blockIdx.x * 4 + wav;
    if (p >= hw) return;
    const _Float16* row = S + ((long)b * hw + p) * ni;
    unsigned short* orow = aw + ((long)b * hw + p) * ni;
    float m = -1e30f;
    for (int n = lane; n < ni; n += 64) m = fmaxf(m, (float)row[n]);
    for (int off = 32; off > 0; off >>= 1) m = fmaxf(m, __shfl_xor(m, off));
    float s = 0.f;
    for (int n = lane; n < ni; n += 64) s += __expf((float)row[n] - m);
    for (int off = 32; off > 0; off >>= 1) s += __shfl_xor(s, off);
    float inv = 1.f / s;
    for (int n = lane; n < ni; n += 64)
        orow[n] = f2bf(__expf((float)row[n] - m) * inv);
}

// ==== lcr[b,col] = 1/max(||g2[b,:,col]||,eps) ==============================
__global__ void lcRnorm(const float* __restrict__ g2, float* __restrict__ lcr)
{
    int b = blockIdx.y;
    int col = blockIdx.x * 256 + threadIdx.x;
    if (col >= GG) return;
    const float* gb = g2 + (long)b * CC * GG + col;
    float ss = 0.f;
    for (int o = 0; o < CC; ++o) { float v = gb[o * GG]; ss += v * v; }
    lcr[b * GG + col] = 1.f / fmaxf(sqrtf(ss), 1e-12f);
}

// ==== lcnT[b,n,o] (normalized) + lcB[b,o,n] (raw), both bf16 ===============
__global__ void buildLc(const float* __restrict__ g2, const float* __restrict__ lcr,
                        unsigned short* __restrict__ lcnT, unsigned short* __restrict__ lcB,
                        int ni, int ptr)
{
    long t = (long)blockIdx.x * 256 + threadIdx.x;
    if (t >= (long)BB * ni * CC) return;
    int o = (int)(t & (CC - 1));
    long r = t >> 8;
    int n = (int)(r % ni);
    int b = (int)(r / ni);
    float raw = g2[(long)b * CC * GG + (long)o * GG + ptr + n];
    lcnT[t] = f2bf(raw * lcr[b * GG + ptr + n]);
    lcB[((long)b * CC + o) * ni + n] = f2bf(raw);
}

// ==== per-position 1/||q[:,p]|| from f16 q (CC rows) =======================
__global__ void qNormCol(const _Float16* __restrict__ q, float* __restrict__ scl, int hw)
{
    int b = blockIdx.y;
    int p = blockIdx.x * 256 + threadIdx.x;
    if (p >= hw) return;
    const _Float16* qb = q + (long)b * CC * hw + p;
    float ss = 0.f;
    for (int o = 0; o < CC; ++o) { float v = (float)qb[(long)o * hw]; ss += v * v; }
    scl[(long)b * hw + p] = 1.f / fmaxf(sqrtf(ss), 1e-12f);
}

// ==== misc =================================================================
__global__ void cvtW(const float* __restrict__ src, unsigned short* __restrict__ dst, int n)
{
    int i = blockIdx.x * 256 + threadIdx.x;
    if (i < n) dst[i] = f2bf(src[i]);
}
__global__ void zeroF(float* __restrict__ p, int n)
{
    int i = blockIdx.x * 256 + threadIdx.x;
    if (i < n) p[i] = 0.f;
}

// ===========================================================================
extern "C" void kernel_launch(void* const* d_in, const int* in_sizes, int n_in,
                              void* d_out, int out_size, void* d_ws, size_t ws_size,
                              hipStream_t stream)
{
    (void)n_in; (void)out_size; (void)ws_size;
    static const int  CI[4]  = {256, 512, 1024, 2048};
    static const int  NI[4]  = {256, 192, 128, 64};
    static const int  HWs[4] = {10000, 2500, 625, 169};
    static const int  PTR[4] = {0, 256, 448, 576};
    static const long OUTOFF[4] = {0, 20480000L, 25600000L, 26880000L};

    const float* feat[4];
    for (int i = 0; i < 4; ++i) feat[i] = (const float*)d_in[i];

    const float *w_sem[4], *w_emb[4], *w_q[4], *w_out[4], *w_res[4];
    bool grouped = (in_sizes[5] == 192 * 512);
    for (int i = 0; i < 4; ++i) {
        if (grouped) {
            w_sem[i] = (const float*)d_in[4 + i];
            w_emb[i] = (const float*)d_in[8 + i];
            w_q[i]   = (const float*)d_in[12 + i];
            w_out[i] = (const float*)d_in[16 + i];
            w_res[i] = (const float*)d_in[20 + i];
        } else {
            int base = 4 + 5 * i;
            w_sem[i] = (const float*)d_in[base + 0];
            w_emb[i] = (const float*)d_in[base + 1];
            w_q[i]   = (const float*)d_in[base + 2];
            w_out[i] = (const float*)d_in[base + 3];
            w_res[i] = (const float*)d_in[base + 4];
        }
    }
    const float* gw1 = (const float*)d_in[24];
    const float* gb1 = (const float*)d_in[25];
    const float* gw2 = (const float*)d_in[26];
    const float* gb2 = (const float*)d_in[27];
    const float* gw3 = (const float*)d_in[28];
    const float* gb3 = (const float*)d_in[29];
    const float* mw1 = (const float*)d_in[30];
    const float* mb1 = (const float*)d_in[31];
    const float* mw2 = (const float*)d_in[32];
    const float* mb2 = (const float*)d_in[33];
    const float* mw3 = (const float*)d_in[34];
    const float* mb3 = (const float*)d_in[35];

    // ---------------- workspace carve-up (184.6 MB, == round-0 footprint) --
    char* wp = (char*)d_ws;
    auto carve = [&](size_t bytes) { char* r = wp; wp += (bytes + 255) & ~(size_t)255; return r; };
    unsigned short* R1 = (unsigned short*)carve(40960000);  // featT bf16
    unsigned short* R2 = (unsigned short*)carve(40960000);  // sem f16 / q f16 / wcT bf16
    unsigned short* R3 = (unsigned short*)carve(40960000);  // embB bf16 / qnT bf16 / aw bf16
    unsigned short* R4 = (unsigned short*)carve(40960000);  // attn bf16 / scores f16
    float* ctxg = (float*)carve(5242880);
    float* gbuf = (float*)carve(5242880);
    float* g2   = (float*)carve(5242880);
    float* h1   = (float*)carve(1310720);   // GCN scratch; doubles as wbuf
    float* h2   = (float*)carve(1310720);
    unsigned short* lcnT = (unsigned short*)carve(1048576);
    unsigned short* lcB  = (unsigned short*)carve(1048576);
    float* lcr  = (float*)carve(20480);
    float* scl  = (float*)carve(320000);
    unsigned short* wbuf = (unsigned short*)h1;  // weight bf16 scratch (phases only)

    float* outp = (float*)d_out;

    auto mg = [&](const unsigned short* A, long sA, int lda,
                  const unsigned short* Bp, long sB, int ldb,
                  void* Cp, long sC, int ldc, long offC,
                  int M, int N, int K, int mode, int kc) {
        if (kc < 1) kc = 1;
        int kLen = ((K + kc - 1) / kc + 31) & ~31;
        int kcc = (K + kLen - 1) / kLen;
        dim3 g((N + 127) / 128, (M + 127) / 128, BB * kcc);
        mfmaGemm<<<g, 256, 0, stream>>>(A, sA, lda, Bp, sB, ldb,
                                        Cp, sC, ldc, offC, M, N, K, kcc, kLen, mode);
    };
    auto launchA = [&](const float* W, long sW,
                       const float* X, long sX, int ldx, long offX,
                       float* Cd, long sC, int ldc, long offC,
                       const float* bias,
                       const float* res, long sR, int ldr, long offR,
                       int O, int K, int P, int relu, int accum) {
        dim3 g((P + 63) / 64, (O + 63) / 64, BB);
        gemmA<<<g, 256, 0, stream>>>(W, sW, X, sX, ldx, offX, Cd, sC, ldc, offC,
                                     bias, res, sR, ldr, offR, O, K, P, relu, accum);
    };
    auto cvt = [&](const float* src, unsigned short* dst, int n) {
        cvtW<<<dim3((n + 255) / 256), 256, 0, stream>>>(src, dst, n);
    };

    zeroF<<<dim3((BB * CC * GG + 255) / 256), 256, 0, stream>>>(ctxg, BB * CC * GG);

    // ---------------- Phase 1: per-level attention -> ctxg -----------------
    for (int i = 0; i < 4; ++i) {
        int ci = CI[i], ni = NI[i], hw = HWs[i];
        // featT = transpose(feat) bf16  (hw, ci)
        transCvtF<<<dim3((hw + 31) / 32, (ci + 31) / 32, BB), 256, 0, stream>>>(
            feat[i], (long)ci * hw, ci, hw, R1, (long)hw * ci, nullptr, 0);
        posStatsT<<<dim3(hw, BB), 256, 0, stream>>>(R1, scl, ci, hw, sqrtf((float)ci));
        // sem = w_sem @ f -> R2 f16 (ni, hw)
        cvt(w_sem[i], wbuf, ni * ci);
        mg(wbuf, 0, ci, R1, (long)hw * ci, ci,
           R2, (long)ni * hw, hw, 0, ni, hw, ci, 3, 1);
        enScale<<<dim3((hw + 255) / 256, BB), 256, 0, stream>>>((const _Float16*)R2, scl, ni, hw);
        // emb = w_emb @ f -> R3 bf16 (256, hw)
        cvt(w_emb[i], wbuf, CC * ci);
        mg(wbuf, 0, ci, R1, (long)hw * ci, ci,
           R3, (long)CC * hw, hw, 0, CC, hw, ci, 4, 1);
        // attn = softmax_p(sem*scl) -> R4 bf16 (ni, hw)
        softmaxHW<<<dim3(ni, BB), 256, 0, stream>>>((const _Float16*)R2, scl, R4, ni, hw);
        // ctx += emb @ attn^T -> ctxg fp32 (atomic split-K)
        int mT = 2, nT = (ni + 127) / 128;
        int kc = 512 / (mT * nT * BB); if (kc < 1) kc = 1;
        mg(R3, (long)CC * hw, hw, R4, (long)ni * hw, hw,
           ctxg, (long)CC * GG, GG, PTR[i], CC, ni, hw, 2, kc);
    }

    // ---------------- GCN per level + residual -> gbuf ---------------------
    for (int i = 0; i < 4; ++i) {
        int ni = NI[i];
        launchA(gw1 + (long)i * 64 * CC, 0, ctxg, (long)CC * GG, GG, PTR[i],
                h1, (long)64 * GG, GG, PTR[i], gb1 + i * 64, nullptr, 0, 0, 0,
                64, CC, ni, 1, 0);
        launchA(gw2 + (long)i * 64 * 64, 0, h1, (long)64 * GG, GG, PTR[i],
                h2, (long)64 * GG, GG, PTR[i], gb2 + i * 64, nullptr, 0, 0, 0,
                64, 64, ni, 1, 0);
        launchA(gw3 + (long)i * CC * 64, 0, h2, (long)64 * GG, GG, PTR[i],
                gbuf, (long)CC * GG, GG, PTR[i], gb3 + i * CC,
                ctxg, (long)CC * GG, GG, PTR[i],
                CC, 64, ni, 0, 0);
    }
    // ---------------- Master GCN + residual -> g2 --------------------------
    launchA(mw1, 0, gbuf, (long)CC * GG, GG, 0, h1, (long)64 * GG, GG, 0,
            mb1, nullptr, 0, 0, 0, 64, CC, GG, 1, 0);
    launchA(mw2, 0, h1, (long)64 * GG, GG, 0, h2, (long)64 * GG, GG, 0,
            mb2, nullptr, 0, 0, 0, 64, 64, GG, 1, 0);
    launchA(mw3, 0, h2, (long)64 * GG, GG, 0, g2, (long)CC * GG, GG, 0,
            mb3, gbuf, (long)CC * GG, GG, 0, CC, 64, GG, 0, 0);

    lcRnorm<<<dim3(3, BB), 256, 0, stream>>>(g2, lcr);

    // ---------------- Phase 2: per-level read-out attention ----------------
    for (int i = 0; i < 4; ++i) {
        int ci = CI[i], ni = NI[i], hw = HWs[i];
        long tot = (long)BB * ni * CC;
        buildLc<<<dim3((unsigned)((tot + 255) / 256)), 256, 0, stream>>>(
            g2, lcr, lcnT, lcB, ni, PTR[i]);
        // featT again
        transCvtF<<<dim3((hw + 31) / 32, (ci + 31) / 32, BB), 256, 0, stream>>>(
            feat[i], (long)ci * hw, ci, hw, R1, (long)hw * ci, nullptr, 0);
        // q = w_q @ f -> R2 f16 (256, hw)
        cvt(w_q[i], wbuf, CC * ci);
        mg(wbuf, 0, ci, R1, (long)hw * ci, ci,
           R2, (long)CC * hw, hw, 0, CC, hw, ci, 3, 1);
        qNormCol<<<dim3((hw + 255) / 256, BB), 256, 0, stream>>>((const _Float16*)R2, scl, hw);
        // qnT = transpose(q)*scl -> R3 bf16 (hw, 256)
        transCvtH<<<dim3((hw + 31) / 32, (CC + 31) / 32, BB), 256, 0, stream>>>(
            (const _Float16*)R2, (long)CC * hw, CC, hw, R3, (long)hw * CC, scl, hw);
        // scores = qnT @ lcnT^T -> R4 f16 (hw, ni)
        mg(R3, (long)hw * CC, CC, lcnT, (long)ni * CC, CC,
           R4, (long)hw * ni, ni, 0, hw, ni, CC, 3, 1);
        // aw = softmax_n -> R3 bf16 (hw, ni)   (qnT dead)
        softmaxN<<<dim3((hw + 3) / 4, BB), 256, 0, stream>>>((const _Float16*)R4, R3, hw, ni);
        // wcT = aw @ lcB^T -> R2 bf16 (hw, 256)   (q dead)
        mg(R3, (long)hw * ni, ni, lcB, (long)CC * ni, ni,
           R2, (long)hw * CC, CC, 0, hw, CC, ni, 4, 1);
        // out = w_res @ f  (store)
        cvt(w_res[i], wbuf, CC * ci);
        mg(wbuf, 0, ci, R1, (long)hw * ci, ci,
           outp, (long)CC * hw, hw, OUTOFF[i], CC, hw, ci, 0, 1);
        // out += w_out @ wc  (accum)
        cvt(w_out[i], wbuf, CC * CC);
        mg(wbuf, 0, CC, R2, (long)hw * CC, CC,
           outp, (long)CC * hw, hw, OUTOFF[i], CC, hw, CC, 1, 1);
    }
}

// Round 3
// 2208.536 us; speedup vs baseline: 3.9506x; 1.2414x over previous
//
#include <hip/hip_runtime.h>
#include <math.h>

// ---------------------------------------------------------------------------
// MultiLevelGlobalContext — bf16 MFMA + split-K + prefetch.
// Levels: ci={256,512,1024,2048}, hw={10000,2500,625,169}, ni={256,192,128,64}
// B=8, C=256, G=640.
// ---------------------------------------------------------------------------

#define BB 8
#define CC 256
#define GG 640

typedef __attribute__((ext_vector_type(8))) short short8;
typedef __attribute__((ext_vector_type(4))) float f32x4;

__device__ __forceinline__ unsigned short f2bf(float f) {
    unsigned int u = __float_as_uint(f);
    u += 0x7fffu + ((u >> 16) & 1u);
    return (unsigned short)(u >> 16);
}
__device__ __forceinline__ float bf2f(unsigned short h) {
    return __uint_as_float(((unsigned int)h) << 16);
}
__device__ __forceinline__ float h2f(unsigned short h) {
    union { unsigned short u; _Float16 x; } cv; cv.u = h; return (float)cv.x;
}
__device__ __forceinline__ unsigned short f2h(float f) {
    union { unsigned short u; _Float16 x; } cv; cv.x = (_Float16)f; return cv.u;
}

// ===================== bf16 MFMA GEMM: C[b] = A(M,K) @ B(N,K)^T =============
// A, B bf16 (ushort), K contiguous. Register-prefetch double buffer.
// modes: 0 store f32, 1 accum f32, 2 atomicAdd f32, 3 store f16, 4 store bf16
__global__ __launch_bounds__(256) void mfmaGemm(
    const unsigned short* __restrict__ A, long sA, int lda,
    const unsigned short* __restrict__ B, long sB, int ldb,
    void* __restrict__ C, long sC, int ldc, long offC,
    int M, int N, int K, int kChunks, int kChunkLen, int mode)
{
    __shared__ __align__(16) unsigned short As[128 * 40];
    __shared__ __align__(16) unsigned short Bs[128 * 40];

    const int z = blockIdx.z;
    const int b = z / kChunks, chunk = z - b * kChunks;
    const int kbeg = chunk * kChunkLen;
    const int kend = min(K, kbeg + kChunkLen);

    const unsigned short* Ab = A + (long)b * sA;
    const unsigned short* Bb = B + (long)b * sB;
    const int m0 = blockIdx.y * 128, n0 = blockIdx.x * 128;

    const int tid = threadIdx.x;
    const int wave = tid >> 6, lane = tid & 63;
    const int wm = (wave & 1) * 64, wn = (wave >> 1) * 64;
    const int lm = lane & 15, kq = lane >> 4;
    const int lrow = tid >> 2;     // 0..63
    const int q4 = tid & 3;

    const bool alignedA = ((lda & 7) == 0) && ((((size_t)Ab) & 15) == 0);
    const bool alignedB = ((ldb & 7) == 0) && ((((size_t)Bb) & 15) == 0);

    f32x4 acc[4][4];
    #pragma unroll
    for (int i = 0; i < 4; ++i)
        #pragma unroll
        for (int j = 0; j < 4; ++j) acc[i][j] = (f32x4){0.f, 0.f, 0.f, 0.f};

    uint4 pa[2], pb[2];
    auto fetch = [&](int k0) {
        int kg = k0 + q4 * 8;
        int krem = kend - kg;
        #pragma unroll
        for (int l = 0; l < 2; ++l) {
            int row = l * 64 + lrow;
            uint4 va = make_uint4(0u, 0u, 0u, 0u);
            int gm = m0 + row;
            if (gm < M && krem > 0) {
                const unsigned short* src = Ab + (long)gm * lda + kg;
                if (krem >= 8 && alignedA) {
                    va = *(const uint4*)src;
                } else {
                    __align__(16) unsigned short tmp[8] = {0,0,0,0,0,0,0,0};
                    int c = krem < 8 ? krem : 8;
                    for (int j = 0; j < c; ++j) tmp[j] = src[j];
                    va = *(const uint4*)tmp;
                }
            }
            pa[l] = va;
            uint4 vb = make_uint4(0u, 0u, 0u, 0u);
            int gn = n0 + row;
            if (gn < N && krem > 0) {
                const unsigned short* src = Bb + (long)gn * ldb + kg;
                if (krem >= 8 && alignedB) {
                    vb = *(const uint4*)src;
                } else {
                    __align__(16) unsigned short tmp[8] = {0,0,0,0,0,0,0,0};
                    int c = krem < 8 ? krem : 8;
                    for (int j = 0; j < c; ++j) tmp[j] = src[j];
                    vb = *(const uint4*)tmp;
                }
            }
            pb[l] = vb;
        }
    };

    fetch(kbeg);
    for (int k0 = kbeg; k0 < kend; k0 += 32) {
        __syncthreads();
        *(uint4*)&As[lrow * 40 + q4 * 8]        = pa[0];
        *(uint4*)&As[(64 + lrow) * 40 + q4 * 8] = pa[1];
        *(uint4*)&Bs[lrow * 40 + q4 * 8]        = pb[0];
        *(uint4*)&Bs[(64 + lrow) * 40 + q4 * 8] = pb[1];
        __syncthreads();
        if (k0 + 32 < kend) fetch(k0 + 32);   // overlap next loads with MFMA

        short8 af[4], bfr[4];
        #pragma unroll
        for (int mt = 0; mt < 4; ++mt)
            af[mt] = *(const short8*)&As[(wm + mt * 16 + lm) * 40 + kq * 8];
        #pragma unroll
        for (int nt = 0; nt < 4; ++nt)
            bfr[nt] = *(const short8*)&Bs[(wn + nt * 16 + lm) * 40 + kq * 8];
        #pragma unroll
        for (int mt = 0; mt < 4; ++mt)
            #pragma unroll
            for (int nt = 0; nt < 4; ++nt)
                acc[mt][nt] = __builtin_amdgcn_mfma_f32_16x16x32_bf16(
                    af[mt], bfr[nt], acc[mt][nt], 0, 0, 0);
    }

    const long cbase = (long)b * sC + offC;
    #pragma unroll
    for (int mt = 0; mt < 4; ++mt) {
        #pragma unroll
        for (int nt = 0; nt < 4; ++nt) {
            int n_g = n0 + wn + nt * 16 + lm;
            if (n_g >= N) continue;
            #pragma unroll
            for (int r = 0; r < 4; ++r) {
                int m_g = m0 + wm + mt * 16 + kq * 4 + r;
                if (m_g >= M) continue;
                float v = acc[mt][nt][r];
                long ci_ = cbase + (long)m_g * ldc + n_g;
                if (mode == 0)      ((float*)C)[ci_] = v;
                else if (mode == 1) ((float*)C)[ci_] += v;
                else if (mode == 2) atomicAdd(&((float*)C)[ci_], v);
                else if (mode == 3) ((unsigned short*)C)[ci_] = f2h(v);
                else                ((unsigned short*)C)[ci_] = f2bf(v);
            }
        }
    }
}

// ================= fp32 GEMM (GCN layers), with optional per-level fusing ==
__global__ __launch_bounds__(256) void gemmA(
    const float* __restrict__ W, long sW,
    const float* __restrict__ X, long sX, int ldx, long offX,
    float* __restrict__ Cd, long sC, int ldc, long offC,
    const float* __restrict__ bias,
    const float* __restrict__ res, long sR, int ldr, long offR,
    int O, int K, int P, int relu, int accum,
    int lvlFuse, long wStride, int bStride)
{
    __shared__ float Ws[16][64];
    __shared__ float Xs[16][64];
    const int tid = threadIdx.x;
    const int tx = tid & 15;
    const int ty = tid >> 4;
    const int b  = blockIdx.z;
    const int o0 = blockIdx.y * 64;
    const int p0 = blockIdx.x * 64;

    const float* Wp = W;
    const float* bp = bias;
    if (lvlFuse) {
        int lvl = p0 >= 576 ? 3 : p0 >= 448 ? 2 : p0 >= 256 ? 1 : 0;
        Wp += (long)lvl * wStride;
        if (bias) bp += (long)lvl * bStride;
    }
    const float* Wb = Wp + (long)b * sW;
    const float* Xb = X + (long)b * sX + offX;

    float acc[4][4] = {};

    const int wo = tid >> 2;
    const int wk = (tid & 3) * 4;
    const int xp = tid & 63;
    const int xq = tid >> 6;

    for (int k0 = 0; k0 < K; k0 += 16) {
        #pragma unroll
        for (int u = 0; u < 4; ++u) {
            int kk = wk + u;
            float v = 0.f;
            if (o0 + wo < O && k0 + kk < K) v = Wb[(long)(o0 + wo) * K + k0 + kk];
            Ws[kk][wo] = v;
        }
        #pragma unroll
        for (int u = 0; u < 4; ++u) {
            int kk = xq * 4 + u;
            float v = 0.f;
            if (p0 + xp < P && k0 + kk < K) v = Xb[(long)(k0 + kk) * ldx + (p0 + xp)];
            Xs[kk][xp] = v;
        }
        __syncthreads();
        #pragma unroll
        for (int kk = 0; kk < 16; ++kk) {
            float4 wv = *(const float4*)&Ws[kk][ty * 4];
            float4 xv = *(const float4*)&Xs[kk][tx * 4];
            float wa[4] = {wv.x, wv.y, wv.z, wv.w};
            float xa[4] = {xv.x, xv.y, xv.z, xv.w};
            #pragma unroll
            for (int i = 0; i < 4; ++i)
                #pragma unroll
                for (int j = 0; j < 4; ++j)
                    acc[i][j] += wa[i] * xa[j];
        }
        __syncthreads();
    }

    #pragma unroll
    for (int i = 0; i < 4; ++i) {
        int o = o0 + ty * 4 + i;
        if (o >= O) continue;
        #pragma unroll
        for (int j = 0; j < 4; ++j) {
            int p = p0 + tx * 4 + j;
            if (p >= P) continue;
            float v = acc[i][j];
            if (bias) v += bp[o];
            if (relu) v = fmaxf(v, 0.f);
            if (res)  v += res[(long)b * sR + offR + (long)o * ldr + p];
            long ci_ = (long)b * sC + offC + (long)o * ldc + p;
            if (accum) Cd[ci_] += v; else Cd[ci_] = v;
        }
    }
}

// =================== transpose+convert: dst[c][r] = src[r][c]*scale[c] =====
__global__ __launch_bounds__(256) void transCvtF(
    const float* __restrict__ src, long sS, int R, int Cc,
    unsigned short* __restrict__ dst, long sD,
    const float* __restrict__ scale, long sScale)
{
    __shared__ float tile[32][33];
    int b = blockIdx.z;
    int r0 = blockIdx.y * 32, c0 = blockIdx.x * 32;
    const float* sb = src + (long)b * sS;
    unsigned short* db = dst + (long)b * sD;
    int tr = threadIdx.x >> 5, tc = threadIdx.x & 31;
    #pragma unroll
    for (int it = 0; it < 4; ++it) {
        int r = r0 + tr + it * 8, c = c0 + tc;
        tile[tr + it * 8][tc] = (r < R && c < Cc) ? sb[(long)r * Cc + c] : 0.f;
    }
    __syncthreads();
    #pragma unroll
    for (int it = 0; it < 4; ++it) {
        int c = c0 + tr + it * 8;
        int r = r0 + tc;
        if (c < Cc && r < R) {
            float v = tile[tc][tr + it * 8];
            if (scale) v *= scale[(long)b * sScale + c];
            db[(long)c * R + r] = f2bf(v);
        }
    }
}

__global__ __launch_bounds__(256) void transCvtH(
    const unsigned short* __restrict__ src, long sS, int R, int Cc,
    unsigned short* __restrict__ dst, long sD,
    const float* __restrict__ scale, long sScale)
{
    __shared__ float tile[32][33];
    int b = blockIdx.z;
    int r0 = blockIdx.y * 32, c0 = blockIdx.x * 32;
    const unsigned short* sb = src + (long)b * sS;
    unsigned short* db = dst + (long)b * sD;
    int tr = threadIdx.x >> 5, tc = threadIdx.x & 31;
    #pragma unroll
    for (int it = 0; it < 4; ++it) {
        int r = r0 + tr + it * 8, c = c0 + tc;
        tile[tr + it * 8][tc] = (r < R && c < Cc) ? h2f(sb[(long)r * Cc + c]) : 0.f;
    }
    __syncthreads();
    #pragma unroll
    for (int it = 0; it < 4; ++it) {
        int c = c0 + tr + it * 8;
        int r = r0 + tc;
        if (c < Cc && r < R) {
            float v = tile[tc][tr + it * 8];
            if (scale) v *= scale[(long)b * sScale + c];
            db[(long)c * R + r] = f2bf(v);
        }
    }
}

// ====== per-position stats from featT rows ================================
__global__ __launch_bounds__(256) void posStatsT(
    const unsigned short* __restrict__ featT, float* __restrict__ fscale,
    int ci, int hw, float sq)
{
    int b = blockIdx.y, p = blockIdx.x;
    const unsigned short* row = featT + ((long)b * hw + p) * ci;
    float s = 0.f, ss = 0.f;
    for (int c = threadIdx.x; c < ci; c += 256) {
        float v = bf2f(row[c]); s += v; ss += v * v;
    }
    __shared__ float rs[256], rss[256];
    int tid = threadIdx.x;
    rs[tid] = s; rss[tid] = ss; __syncthreads();
    for (int st = 128; st > 0; st >>= 1) {
        if (tid < st) { rs[tid] += rs[tid + st]; rss[tid] += rss[tid + st]; }
        __syncthreads();
    }
    if (tid == 0)
        fscale[(long)b * hw + p] = rs[0] / fmaxf(sqrtf(rss[0]), 1e-12f) * sq;
}

// ==== scale[b,p] = fscale[b,p] / max(||sem[b,:,p]||,eps)  (sem f16) ========
__global__ void enScale(const unsigned short* __restrict__ sem, float* __restrict__ fscale,
                        int ni, int hw)
{
    int b = blockIdx.y;
    int p = blockIdx.x * 256 + threadIdx.x;
    if (p >= hw) return;
    const unsigned short* sb = sem + (long)b * ni * hw + p;
    float ss = 0.f;
    for (int n = 0; n < ni; ++n) { float v = h2f(sb[(long)n * hw]); ss += v * v; }
    fscale[(long)b * hw + p] = fscale[(long)b * hw + p] / fmaxf(sqrtf(ss), 1e-12f);
}

// ==== softmax over p: buf holds sem f16 in, attn bf16 out (IN PLACE) =======
__global__ __launch_bounds__(256) void softmaxHW(
    unsigned short* buf, const float* __restrict__ scale, int ni, int hw)
{
    int b = blockIdx.y, n = blockIdx.x;
    unsigned short* row = buf + ((long)b * ni + n) * hw;
    const float* sc = scale + (long)b * hw;
    __shared__ float red[256];
    int tid = threadIdx.x;

    float m = -1e30f;
    for (int p = tid; p < hw; p += 256) m = fmaxf(m, h2f(row[p]) * sc[p]);
    red[tid] = m; __syncthreads();
    for (int s = 128; s > 0; s >>= 1) {
        if (tid < s) red[tid] = fmaxf(red[tid], red[tid + s]);
        __syncthreads();
    }
    m = red[0]; __syncthreads();

    float sum = 0.f;
    for (int p = tid; p < hw; p += 256) sum += __expf(h2f(row[p]) * sc[p] - m);
    red[tid] = sum; __syncthreads();
    for (int s = 128; s > 0; s >>= 1) {
        if (tid < s) red[tid] += red[tid + s];
        __syncthreads();
    }
    float inv = 1.0f / red[0];

    for (int p = tid; p < hw; p += 256) {
        float v = __expf(h2f(row[p]) * sc[p] - m) * inv;   // read then write
        row[p] = f2bf(v);
    }
}

// ==== softmax over n: buf f16 in, bf16 out (IN PLACE) ======================
__global__ void softmaxN(unsigned short* buf, int hw, int ni)
{
    int b = blockIdx.y;
    int wav = threadIdx.x >> 6, lane = threadIdx.x & 63;
    int p = blockIdx.x * 4 + wav;
    if (p >= hw) return;
    unsigned short* row = buf + ((long)b * hw + p) * ni;
    float m = -1e30f;
    for (int n = lane; n < ni; n += 64) m = fmaxf(m, h2f(row[n]));
    for (int off = 32; off > 0; off >>= 1) m = fmaxf(m, __shfl_xor(m, off));
    float s = 0.f;
    for (int n = lane; n < ni; n += 64) s += __expf(h2f(row[n]) - m);
    for (int off = 32; off > 0; off >>= 1) s += __shfl_xor(s, off);
    float inv = 1.f / s;
    for (int n = lane; n < ni; n += 64) {
        float v = __expf(h2f(row[n]) - m) * inv;
        row[n] = f2bf(v);
    }
}

// ==== lcr[b,col] = 1/max(||g2[b,:,col]||,eps) ==============================
__global__ void lcRnorm(const float* __restrict__ g2, float* __restrict__ lcr)
{
    int b = blockIdx.y;
    int col = blockIdx.x * 256 + threadIdx.x;
    if (col >= GG) return;
    const float* gb = g2 + (long)b * CC * GG + col;
    float ss = 0.f;
    for (int o = 0; o < CC; ++o) { float v = gb[o * GG]; ss += v * v; }
    lcr[b * GG + col] = 1.f / fmaxf(sqrtf(ss), 1e-12f);
}

// ==== lcnT[b,n,o] (normalized) + lcB[b,o,n] (raw), both bf16 ===============
__global__ void buildLc(const float* __restrict__ g2, const float* __restrict__ lcr,
                        unsigned short* __restrict__ lcnT, unsigned short* __restrict__ lcB,
                        int ni, int ptr)
{
    long t = (long)blockIdx.x * 256 + threadIdx.x;
    if (t >= (long)BB * ni * CC) return;
    int o = (int)(t & (CC - 1));
    long r = t >> 8;
    int n = (int)(r % ni);
    int b = (int)(r / ni);
    float raw = g2[(long)b * CC * GG + (long)o * GG + ptr + n];
    lcnT[t] = f2bf(raw * lcr[b * GG + ptr + n]);
    lcB[((long)b * CC + o) * ni + n] = f2bf(raw);
}

// ==== per-position 1/||q[:,p]|| (q f16, CC rows) ===========================
__global__ void qNormCol(const unsigned short* __restrict__ q, float* __restrict__ scl, int hw)
{
    int b = blockIdx.y;
    int p = blockIdx.x * 256 + threadIdx.x;
    if (p >= hw) return;
    const unsigned short* qb = q + (long)b * CC * hw + p;
    float ss = 0.f;
    for (int o = 0; o < CC; ++o) { float v = h2f(qb[(long)o * hw]); ss += v * v; }
    scl[(long)b * hw + p] = 1.f / fmaxf(sqrtf(ss), 1e-12f);
}

// ==== fused weight conversion (all 20 matrices, one launch) ================
struct CvtJob { const float* src; long off; int n; int pad; };
struct CvtJobs { CvtJob j[20]; };
__global__ void cvtAllK(CvtJobs jobs, unsigned short* __restrict__ dst)
{
    const CvtJob J = jobs.j[blockIdx.y];
    int t = blockIdx.x * 256 + threadIdx.x;
    if (t < J.n) dst[J.off + t] = f2bf(J.src[t]);
}

// ==== split-K tail convert: fp32 -> f16/bf16 ===============================
__global__ void cvtOut(const float* __restrict__ src, unsigned short* __restrict__ dst,
                       int n, int toF16)
{
    int i = blockIdx.x * 256 + threadIdx.x;
    if (i >= n) return;
    float v = src[i];
    dst[i] = toF16 ? f2h(v) : f2bf(v);
}

// ===========================================================================
extern "C" void kernel_launch(void* const* d_in, const int* in_sizes, int n_in,
                              void* d_out, int out_size, void* d_ws, size_t ws_size,
                              hipStream_t stream)
{
    (void)n_in; (void)out_size; (void)ws_size;
    static const int  CI[4]  = {256, 512, 1024, 2048};
    static const int  NI[4]  = {256, 192, 128, 64};
    static const int  HWs[4] = {10000, 2500, 625, 169};
    static const int  PTR[4] = {0, 256, 448, 576};
    static const long OUTOFF[4] = {0, 20480000L, 25600000L, 26880000L};

    const float* feat[4];
    for (int i = 0; i < 4; ++i) feat[i] = (const float*)d_in[i];

    const float *w_sem[4], *w_emb[4], *w_q[4], *w_out[4], *w_res[4];
    bool grouped = (in_sizes[5] == 192 * 512);
    for (int i = 0; i < 4; ++i) {
        if (grouped) {
            w_sem[i] = (const float*)d_in[4 + i];
            w_emb[i] = (const float*)d_in[8 + i];
            w_q[i]   = (const float*)d_in[12 + i];
            w_out[i] = (const float*)d_in[16 + i];
            w_res[i] = (const float*)d_in[20 + i];
        } else {
            int base = 4 + 5 * i;
            w_sem[i] = (const float*)d_in[base + 0];
            w_emb[i] = (const float*)d_in[base + 1];
            w_q[i]   = (const float*)d_in[base + 2];
            w_out[i] = (const float*)d_in[base + 3];
            w_res[i] = (const float*)d_in[base + 4];
        }
    }
    const float* gw1 = (const float*)d_in[24];
    const float* gb1 = (const float*)d_in[25];
    const float* gw2 = (const float*)d_in[26];
    const float* gb2 = (const float*)d_in[27];
    const float* gw3 = (const float*)d_in[28];
    const float* gb3 = (const float*)d_in[29];
    const float* mw1 = (const float*)d_in[30];
    const float* mb1 = (const float*)d_in[31];
    const float* mw2 = (const float*)d_in[32];
    const float* mb2 = (const float*)d_in[33];
    const float* mw3 = (const float*)d_in[34];
    const float* mb3 = (const float*)d_in[35];

    // ---------------- workspace carve-up (~157 MB) -------------------------
    char* wp = (char*)d_ws;
    auto carve = [&](size_t bytes) { char* r = wp; wp += (bytes + 255) & ~(size_t)255; return r; };
    unsigned short* R1 = (unsigned short*)carve(40960000);  // featT bf16
    unsigned short* R2 = (unsigned short*)carve(40960000);  // sem/attn | q/scores/aw
    unsigned short* R3 = (unsigned short*)carve(40960000);  // emb | qnT/wcT
    float* ctxg = (float*)carve(5242880);
    float* gbuf = (float*)carve(5242880);
    float* g2   = (float*)carve(5242880);
    float* h1   = (float*)carve(1310720);
    float* h2   = (float*)carve(1310720);
    unsigned short* lcnT = (unsigned short*)carve(1048576);
    unsigned short* lcB  = (unsigned short*)carve(1048576);
    float* lcr  = (float*)carve(20480);
    float* scl  = (float*)carve(320000);
    float* SK   = (float*)carve(5120000);                   // split-K scratch
    unsigned short* wbuf = (unsigned short*)carve(7275520); // all weights bf16

    float* outp = (float*)d_out;

    // ---------------- fused weight conversion ------------------------------
    CvtJobs jobs;
    unsigned short *wsemB[4], *wembB[4], *wqB[4], *woutB[4], *wresB[4];
    long woff = 0; int maxn = 0, jx = 0;
    auto addJob = [&](const float* s, int n, unsigned short** outp_) {
        jobs.j[jx].src = s; jobs.j[jx].off = woff; jobs.j[jx].n = n; jobs.j[jx].pad = 0;
        *outp_ = wbuf + woff;
        woff += (n + 7) & ~7;
        if (n > maxn) maxn = n;
        ++jx;
    };
    for (int i = 0; i < 4; ++i) {
        addJob(w_sem[i], NI[i] * CI[i], &wsemB[i]);
        addJob(w_emb[i], CC * CI[i],    &wembB[i]);
        addJob(w_q[i],   CC * CI[i],    &wqB[i]);
        addJob(w_out[i], CC * CC,       &woutB[i]);
        addJob(w_res[i], CC * CI[i],    &wresB[i]);
    }
    cvtAllK<<<dim3((maxn + 255) / 256, 20), 256, 0, stream>>>(jobs, wbuf);

    auto mg = [&](const unsigned short* A, long sA, int lda,
                  const unsigned short* Bp, long sB, int ldb,
                  void* Cp, long sC, int ldc, long offC,
                  int M, int N, int K, int mode, int kc) {
        if (kc < 1) kc = 1;
        int kLen = ((K + kc - 1) / kc + 31) & ~31;
        int kcc = (K + kLen - 1) / kLen;
        dim3 g((N + 127) / 128, (M + 127) / 128, BB * kcc);
        mfmaGemm<<<g, 256, 0, stream>>>(A, sA, lda, Bp, sB, ldb,
                                        Cp, sC, ldc, offC, M, N, K, kcc, kLen, mode);
    };
    // projection W(M,K)bf16 @ featT(N,K) -> dst contiguous (B,M,N), f16/bf16
    auto projTo = [&](const unsigned short* Wbf, int K, const unsigned short* Xt, long sXt,
                      unsigned short* dst, int M, int N, int fmode) {
        int blocks = ((M + 127) / 128) * ((N + 127) / 128) * BB;
        if (blocks >= 256 || K < 512) {
            mg(Wbf, 0, K, Xt, sXt, K, dst, (long)M * N, N, 0, M, N, K, fmode, 1);
        } else {
            int kc = (256 + blocks - 1) / blocks;
            hipMemsetAsync(SK, 0, (size_t)BB * M * N * 4, stream);
            mg(Wbf, 0, K, Xt, sXt, K, SK, (long)M * N, N, 0, M, N, K, 2, kc);
            long tot = (long)BB * M * N;
            cvtOut<<<dim3((unsigned)((tot + 255) / 256)), 256, 0, stream>>>(
                SK, dst, (int)tot, fmode == 3 ? 1 : 0);
        }
    };

    hipMemsetAsync(ctxg, 0, (size_t)BB * CC * GG * 4, stream);

    // ---------------- Phase 1: per-level attention -> ctxg -----------------
    for (int i = 0; i < 4; ++i) {
        int ci = CI[i], ni = NI[i], hw = HWs[i];
        transCvtF<<<dim3((hw + 31) / 32, (ci + 31) / 32, BB), 256, 0, stream>>>(
            feat[i], (long)ci * hw, ci, hw, R1, (long)hw * ci, nullptr, 0);
        posStatsT<<<dim3(hw, BB), 256, 0, stream>>>(R1, scl, ci, hw, sqrtf((float)ci));
        // sem -> R2 f16
        projTo(wsemB[i], ci, R1, (long)hw * ci, R2, ni, hw, 3);
        enScale<<<dim3((hw + 255) / 256, BB), 256, 0, stream>>>(R2, scl, ni, hw);
        // emb -> R3 bf16
        projTo(wembB[i], ci, R1, (long)hw * ci, R3, CC, hw, 4);
        // attn = softmax_p(sem*scl) in place over R2 (bf16 out)
        softmaxHW<<<dim3(ni, BB), 256, 0, stream>>>(R2, scl, ni, hw);
        // ctx += emb @ attn^T -> ctxg (atomic, split-K when skinny)
        {
            int blocks = ((CC + 127) / 128) * ((ni + 127) / 128) * BB;
            int kc = (blocks < 256 && hw >= 512) ? (256 + blocks - 1) / blocks : 1;
            mg(R3, (long)CC * hw, hw, R2, (long)ni * hw, hw,
               ctxg, (long)CC * GG, GG, PTR[i], CC, ni, hw, 2, kc);
        }
    }

    // ---------------- GCN per level (fused across levels) ------------------
    {
        dim3 gl(GG / 64, 1, BB);
        gemmA<<<gl, 256, 0, stream>>>(gw1, 0, ctxg, (long)CC * GG, GG, 0,
                                      h1, (long)64 * GG, GG, 0, gb1,
                                      nullptr, 0, 0, 0, 64, CC, GG, 1, 0,
                                      1, (long)64 * CC, 64);
        gemmA<<<gl, 256, 0, stream>>>(gw2, 0, h1, (long)64 * GG, GG, 0,
                                      h2, (long)64 * GG, GG, 0, gb2,
                                      nullptr, 0, 0, 0, 64, 64, GG, 1, 0,
                                      1, (long)64 * 64, 64);
        dim3 gl2(GG / 64, CC / 64, BB);
        gemmA<<<gl2, 256, 0, stream>>>(gw3, 0, h2, (long)64 * GG, GG, 0,
                                       gbuf, (long)CC * GG, GG, 0, gb3,
                                       ctxg, (long)CC * GG, GG, 0, CC, 64, GG, 0, 0,
                                       1, (long)CC * 64, CC);
    }
    // ---------------- Master GCN + residual -> g2 --------------------------
    {
        dim3 gl(GG / 64, 1, BB);
        gemmA<<<gl, 256, 0, stream>>>(mw1, 0, gbuf, (long)CC * GG, GG, 0,
                                      h1, (long)64 * GG, GG, 0, mb1,
                                      nullptr, 0, 0, 0, 64, CC, GG, 1, 0, 0, 0, 0);
        gemmA<<<gl, 256, 0, stream>>>(mw2, 0, h1, (long)64 * GG, GG, 0,
                                      h2, (long)64 * GG, GG, 0, mb2,
                                      nullptr, 0, 0, 0, 64, 64, GG, 1, 0, 0, 0, 0);
        dim3 gl2(GG / 64, CC / 64, BB);
        gemmA<<<gl2, 256, 0, stream>>>(mw3, 0, h2, (long)64 * GG, GG, 0,
                                       g2, (long)CC * GG, GG, 0, mb3,
                                       gbuf, (long)CC * GG, GG, 0, CC, 64, GG, 0, 0, 0, 0, 0);
    }

    lcRnorm<<<dim3(3, BB), 256, 0, stream>>>(g2, lcr);

    // ---------------- Phase 2: per-level read-out attention ----------------
    for (int i = 0; i < 4; ++i) {
        int ci = CI[i], ni = NI[i], hw = HWs[i];
        long tot = (long)BB * ni * CC;
        buildLc<<<dim3((unsigned)((tot + 255) / 256)), 256, 0, stream>>>(
            g2, lcr, lcnT, lcB, ni, PTR[i]);
        transCvtF<<<dim3((hw + 31) / 32, (ci + 31) / 32, BB), 256, 0, stream>>>(
            feat[i], (long)ci * hw, ci, hw, R1, (long)hw * ci, nullptr, 0);
        // q -> R2 f16
        projTo(wqB[i], ci, R1, (long)hw * ci, R2, CC, hw, 3);
        qNormCol<<<dim3((hw + 255) / 256, BB), 256, 0, stream>>>(R2, scl, hw);
        // qnT = transpose(q)*scl -> R3 bf16 (hw, 256)
        transCvtH<<<dim3((hw + 31) / 32, (CC + 31) / 32, BB), 256, 0, stream>>>(
            R2, (long)CC * hw, CC, hw, R3, (long)hw * CC, scl, hw);
        // scores = qnT @ lcnT^T -> R2 f16 (hw, ni)   (q dead)
        mg(R3, (long)hw * CC, CC, lcnT, (long)ni * CC, CC,
           R2, (long)hw * ni, ni, 0, hw, ni, CC, 3, 1);
        // aw = softmax_n in place over R2 (bf16 out)
        softmaxN<<<dim3((hw + 3) / 4, BB), 256, 0, stream>>>(R2, hw, ni);
        // wcT = aw @ lcB^T -> R3 bf16 (hw, 256)   (qnT dead)
        mg(R2, (long)hw * ni, ni, lcB, (long)CC * ni, ni,
           R3, (long)hw * CC, CC, 0, hw, CC, ni, 4, 1);
        // out = w_res @ f  (split-K atomic into zeroed region when skinny)
        {
            int blocks = ((CC + 127) / 128) * ((hw + 127) / 128) * BB;
            if (blocks >= 256 || ci < 512) {
                mg(wresB[i], 0, ci, R1, (long)hw * ci, ci,
                   outp, (long)CC * hw, hw, OUTOFF[i], CC, hw, ci, 0, 1);
            } else {
                int kc = (256 + blocks - 1) / blocks;
                hipMemsetAsync(outp + OUTOFF[i], 0, (size_t)BB * CC * hw * 4, stream);
                mg(wresB[i], 0, ci, R1, (long)hw * ci, ci,
                   outp, (long)CC * hw, hw, OUTOFF[i], CC, hw, ci, 2, kc);
            }
        }
        // out += w_out @ wc
        mg(woutB[i], 0, CC, R3, (long)hw * CC, CC,
           outp, (long)CC * hw, hw, OUTOFF[i], CC, hw, CC, 1, 1);
    }
}